// Round 1
// baseline (103.121 us; speedup 1.0000x reference)
//
#include <hip/hip_runtime.h>
#include <cstdint>

#define N_PRED 8192
#define N_GT   32768

// ---- ws layout ----
// [0,      65536)  : u64 keys[8192]   (NN argmin: (dist_bits<<32)|gt_idx)
// [65536,  98304)  : u32 repmin[8192] (repulsion min sq-dist bits)
// [98304,  98688)  : float partials[32][3] (att, nrm, rep per finalize block)

__global__ __launch_bounds__(256) void init_ws_kernel(unsigned long long* keys,
                                                      unsigned int* repmin) {
    int i = blockIdx.x * blockDim.x + threadIdx.x;
    if (i < N_PRED) {
        keys[i]   = 0xFFFFFFFFFFFFFFFFull;
        repmin[i] = 0xFFFFFFFFu;
    }
}

// ---- NN search: pred (8192) vs gt (32768) ----
// PP=4 pred points per thread, 256 thr/block -> pred chunk = 1024 (8 chunks)
// gt tile = 512 -> 64 gt chunks. Grid = 8*64 = 512 blocks.
#define PP      4
#define NN_BLK  256
#define GT_TILE 512
#define N_GTC   (N_GT / GT_TILE)            // 64
#define PRED_CHUNK (PP * NN_BLK)            // 1024

__global__ __launch_bounds__(256) void nn_kernel(const float* __restrict__ pred,
                                                 const float* __restrict__ gt,
                                                 unsigned long long* __restrict__ keys) {
    __shared__ float sx[GT_TILE], sy[GT_TILE], sz[GT_TILE];
    const int pc = blockIdx.x / N_GTC;
    const int gc = blockIdx.x % N_GTC;
    const int gbase = gc * GT_TILE;

    for (int k = threadIdx.x; k < GT_TILE; k += NN_BLK) {
        const int g = gbase + k;
        sx[k] = gt[g * 6 + 0];
        sy[k] = gt[g * 6 + 1];
        sz[k] = gt[g * 6 + 2];
    }
    __syncthreads();

    float px[PP], py[PP], pz[PP], best[PP];
    int   pidx[PP], bj[PP];
#pragma unroll
    for (int q = 0; q < PP; ++q) {
        const int p = pc * PRED_CHUNK + q * NN_BLK + threadIdx.x;
        pidx[q] = p;
        px[q] = pred[p * 6 + 0];
        py[q] = pred[p * 6 + 1];
        pz[q] = pred[p * 6 + 2];
        best[q] = 3.0e38f;
        bj[q] = 0;
    }

#pragma unroll 4
    for (int k = 0; k < GT_TILE; ++k) {
        const float gx = sx[k], gy = sy[k], gz = sz[k];
#pragma unroll
        for (int q = 0; q < PP; ++q) {
            const float dx = px[q] - gx;
            const float dy = py[q] - gy;
            const float dz = pz[q] - gz;
            const float d = dx * dx + dy * dy + dz * dz;
            if (d < best[q]) { best[q] = d; bj[q] = k; }
        }
    }

#pragma unroll
    for (int q = 0; q < PP; ++q) {
        const unsigned long long key =
            ((unsigned long long)__float_as_uint(best[q]) << 32) |
            (unsigned long long)(unsigned)(gbase + bj[q]);
        atomicMin(&keys[pidx[q]], key);
    }
}

// ---- Repulsion: pred vs pred, exclude self ----
// PP=4, 256 thr -> pred chunk 1024 (8 chunks); self tile = 256 -> 32 chunks.
// Grid = 8*32 = 256 blocks.
#define ST 256
#define N_SC (N_PRED / ST)                  // 32

__global__ __launch_bounds__(256) void rep_kernel(const float* __restrict__ pred,
                                                  unsigned int* __restrict__ repmin) {
    __shared__ float sx[ST], sy[ST], sz[ST];
    const int pc = blockIdx.x / N_SC;
    const int sc = blockIdx.x % N_SC;
    const int sbase = sc * ST;

    for (int k = threadIdx.x; k < ST; k += NN_BLK) {
        const int g = sbase + k;
        sx[k] = pred[g * 6 + 0];
        sy[k] = pred[g * 6 + 1];
        sz[k] = pred[g * 6 + 2];
    }
    __syncthreads();

    float px[PP], py[PP], pz[PP], best[PP];
    int pidx[PP];
#pragma unroll
    for (int q = 0; q < PP; ++q) {
        const int p = pc * PRED_CHUNK + q * NN_BLK + threadIdx.x;
        pidx[q] = p;
        px[q] = pred[p * 6 + 0];
        py[q] = pred[p * 6 + 1];
        pz[q] = pred[p * 6 + 2];
        best[q] = 3.0e38f;
    }

#pragma unroll 4
    for (int k = 0; k < ST; ++k) {
        const float gx = sx[k], gy = sy[k], gz = sz[k];
        const int j = sbase + k;
#pragma unroll
        for (int q = 0; q < PP; ++q) {
            const float dx = px[q] - gx;
            const float dy = py[q] - gy;
            const float dz = pz[q] - gz;
            float d = dx * dx + dy * dy + dz * dz;
            if (j == pidx[q]) d = 3.0e38f;   // exclude self
            if (d < best[q]) best[q] = d;
        }
    }

#pragma unroll
    for (int q = 0; q < PP; ++q) {
        atomicMin(&repmin[pidx[q]], __float_as_uint(best[q]));
    }
}

// ---- Finalize: per-point losses + deterministic block partial sums ----
__device__ inline float wave_reduce(float v) {
#pragma unroll
    for (int off = 32; off > 0; off >>= 1) v += __shfl_down(v, off, 64);
    return v;
}

__global__ __launch_bounds__(256) void finalize_kernel(const float* __restrict__ pred,
                                                       const float* __restrict__ gt,
                                                       const unsigned long long* __restrict__ keys,
                                                       const unsigned int* __restrict__ repmin,
                                                       float* __restrict__ partials) {
    const int p = blockIdx.x * blockDim.x + threadIdx.x;

    const unsigned long long key = keys[p];
    const int j = (int)(key & 0xFFFFFFFFull);

    const float px = pred[p * 6 + 0], py = pred[p * 6 + 1], pz = pred[p * 6 + 2];
    const float gx = gt[j * 6 + 0],  gy = gt[j * 6 + 1],  gz = gt[j * 6 + 2];
    const float dx = px - gx, dy = py - gy, dz = pz - gz;
    float att = dx * dx + dy * dy + dz * dz;   // summed over 3 coords

    const float pnx = pred[p * 6 + 3], pny = pred[p * 6 + 4], pnz = pred[p * 6 + 5];
    const float gnx = gt[j * 6 + 3],   gny = gt[j * 6 + 4],   gnz = gt[j * 6 + 5];
    const float pl = fmaxf(sqrtf(pnx * pnx + pny * pny + pnz * pnz), 1e-5f);
    const float gl = fmaxf(sqrtf(gnx * gnx + gny * gny + gnz * gnz), 1e-5f);
    const float cosv = (pnx * gnx + pny * gny + pnz * gnz) / (pl * gl);
    float nrm = 1.0f - cosv;

    const float dmin = sqrtf(__uint_as_float(repmin[p]));
    const float x = 100.0f * (0.3f - dmin);
    const float sp = fmaxf(x, 0.0f) + log1pf(expf(-fabsf(x)));
    float rep = sp * sp;

    att = wave_reduce(att);
    nrm = wave_reduce(nrm);
    rep = wave_reduce(rep);

    __shared__ float red[3][4];
    const int wave = threadIdx.x >> 6;
    const int lane = threadIdx.x & 63;
    if (lane == 0) {
        red[0][wave] = att;
        red[1][wave] = nrm;
        red[2][wave] = rep;
    }
    __syncthreads();
    if (threadIdx.x == 0) {
        float a = red[0][0] + red[0][1] + red[0][2] + red[0][3];
        float n = red[1][0] + red[1][1] + red[1][2] + red[1][3];
        float r = red[2][0] + red[2][1] + red[2][2] + red[2][3];
        partials[blockIdx.x * 3 + 0] = a;
        partials[blockIdx.x * 3 + 1] = n;
        partials[blockIdx.x * 3 + 2] = r;
    }
}

__global__ void combine_kernel(const float* __restrict__ partials, float* __restrict__ out) {
    if (threadIdx.x == 0 && blockIdx.x == 0) {
        float a = 0.f, n = 0.f, r = 0.f;
        for (int b = 0; b < 32; ++b) {
            a += partials[b * 3 + 0];
            n += partials[b * 3 + 1];
            r += partials[b * 3 + 2];
        }
        const float attraction = a / (float)(N_PRED * 3);
        const float norm_loss  = n / (float)N_PRED;
        const float repulsion  = r / (float)N_PRED;
        out[0] = attraction + repulsion + 10.0f * norm_loss;
    }
}

extern "C" void kernel_launch(void* const* d_in, const int* in_sizes, int n_in,
                              void* d_out, int out_size, void* d_ws, size_t ws_size,
                              hipStream_t stream) {
    const float* pred = (const float*)d_in[0];   // (8192, 6)
    const float* gt   = (const float*)d_in[3];   // (32768, 6)
    float* out = (float*)d_out;

    char* ws = (char*)d_ws;
    unsigned long long* keys = (unsigned long long*)(ws);
    unsigned int* repmin     = (unsigned int*)(ws + 65536);
    float* partials          = (float*)(ws + 98304);

    init_ws_kernel<<<N_PRED / 256, 256, 0, stream>>>(keys, repmin);
    nn_kernel<<<(N_PRED / PRED_CHUNK) * N_GTC, NN_BLK, 0, stream>>>(pred, gt, keys);
    rep_kernel<<<(N_PRED / PRED_CHUNK) * N_SC, NN_BLK, 0, stream>>>(pred, repmin);
    finalize_kernel<<<N_PRED / 256, 256, 0, stream>>>(pred, gt, keys, repmin, partials);
    combine_kernel<<<1, 64, 0, stream>>>(partials, out);
}

// Round 2
// 64.017 us; speedup vs baseline: 1.6108x; 1.6108x over previous
//
#include <hip/hip_runtime.h>
#include <cstdint>

#define N_PRED 8192
#define N_GT   32768
#define COFF   64.0f      // positivity offset: h = C + p.g - 0.5*|g|^2 in (15, 96)

// ---- ws layout ----
// [0,     65536) : u64 keys[8192]   (NN argmax key: (packed_h_bits<<32)|gt_idx)
// [65536, 98304) : u32 repmax[8192] (repulsion max h bits, h > 0)
// [98304, 98688) : float partials[32][3]

__global__ __launch_bounds__(256) void init_ws_kernel(unsigned long long* keys,
                                                      unsigned int* repmax) {
    int i = blockIdx.x * blockDim.x + threadIdx.x;
    if (i < N_PRED) {
        keys[i]   = 0ull;
        repmax[i] = 0u;
    }
}

// ---- NN search: argmax over gt of h = C + p.g - 0.5|g|^2  (== argmin dist) ----
// PP=4 pred/thread, 256 thr -> pred chunk 1024 (8 chunks); gt tile 512 -> 64 chunks.
#define PP      4
#define NN_BLK  256
#define GT_TILE 512
#define N_GTC   (N_GT / GT_TILE)            // 64
#define PRED_CHUNK (PP * NN_BLK)            // 1024

__global__ __launch_bounds__(256) void nn_kernel(const float* __restrict__ pred,
                                                 const float* __restrict__ gt,
                                                 unsigned long long* __restrict__ keys) {
    __shared__ float4 tile4[GT_TILE];
    const int pc = blockIdx.x / N_GTC;
    const int gc = blockIdx.x % N_GTC;
    const int gbase = gc * GT_TILE;

    for (int k = threadIdx.x; k < GT_TILE; k += NN_BLK) {
        const int g = gbase + k;
        const float x = gt[g * 6 + 0];
        const float y = gt[g * 6 + 1];
        const float z = gt[g * 6 + 2];
        const float w = COFF - 0.5f * (x * x + y * y + z * z);
        tile4[k] = make_float4(x, y, z, w);
    }
    __syncthreads();

    float px[PP], py[PP], pz[PP];
    unsigned int best[PP];
    int pidx[PP];
#pragma unroll
    for (int q = 0; q < PP; ++q) {
        const int p = pc * PRED_CHUNK + q * NN_BLK + threadIdx.x;
        pidx[q] = p;
        px[q] = pred[p * 6 + 0];
        py[q] = pred[p * 6 + 1];
        pz[q] = pred[p * 6 + 2];
        best[q] = 0u;
    }

#pragma unroll 8
    for (int k = 0; k < GT_TILE; ++k) {
        const float4 g4 = tile4[k];
#pragma unroll
        for (int q = 0; q < PP; ++q) {
            const float t = fmaf(px[q], g4.x, fmaf(py[q], g4.y, fmaf(pz[q], g4.z, g4.w)));
            const unsigned int key = (__float_as_uint(t) & 0xFFFFFE00u) | (unsigned int)k;
            best[q] = best[q] > key ? best[q] : key;
        }
    }

#pragma unroll
    for (int q = 0; q < PP; ++q) {
        const unsigned int kq = best[q] & 0x1FFu;
        const unsigned long long key64 =
            ((unsigned long long)best[q] << 32) | (unsigned long long)(unsigned)(gbase + kq);
        atomicMax(&keys[pidx[q]], key64);
    }
}

// ---- Repulsion: max over j!=i of h = C + pi.pj - 0.5|pj|^2 (exact fp32) ----
// PP=4, pred chunk 1024 (8 chunks); j tile 256 -> 32 chunks. Grid = 256 blocks.
#define ST 256
#define N_SC (N_PRED / ST)                  // 32

__global__ __launch_bounds__(256) void rep_kernel(const float* __restrict__ pred,
                                                  unsigned int* __restrict__ repmax) {
    __shared__ float4 tile4[ST];
    const int pc = blockIdx.x / N_SC;
    const int sc = blockIdx.x % N_SC;
    const int sbase = sc * ST;
    const int pcbase = pc * PRED_CHUNK;

    for (int k = threadIdx.x; k < ST; k += NN_BLK) {
        const int g = sbase + k;
        const float x = pred[g * 6 + 0];
        const float y = pred[g * 6 + 1];
        const float z = pred[g * 6 + 2];
        const float w = COFF - 0.5f * (x * x + y * y + z * z);
        tile4[k] = make_float4(x, y, z, w);
    }
    __syncthreads();

    float px[PP], py[PP], pz[PP], best[PP];
    int pidx[PP];
#pragma unroll
    for (int q = 0; q < PP; ++q) {
        const int p = pcbase + q * NN_BLK + threadIdx.x;
        pidx[q] = p;
        px[q] = pred[p * 6 + 0];
        py[q] = pred[p * 6 + 1];
        pz[q] = pred[p * 6 + 2];
        best[q] = 0.0f;
    }

    const bool excl = (sbase >= pcbase) && (sbase < pcbase + PRED_CHUNK);
    if (excl) {
#pragma unroll 4
        for (int k = 0; k < ST; ++k) {
            const float4 g4 = tile4[k];
            const int j = sbase + k;
#pragma unroll
            for (int q = 0; q < PP; ++q) {
                float t = fmaf(px[q], g4.x, fmaf(py[q], g4.y, fmaf(pz[q], g4.z, g4.w)));
                t = (j == pidx[q]) ? 0.0f : t;   // h > 0 always, so 0 never wins
                best[q] = fmaxf(best[q], t);
            }
        }
    } else {
#pragma unroll 8
        for (int k = 0; k < ST; ++k) {
            const float4 g4 = tile4[k];
#pragma unroll
            for (int q = 0; q < PP; ++q) {
                const float t = fmaf(px[q], g4.x, fmaf(py[q], g4.y, fmaf(pz[q], g4.z, g4.w)));
                best[q] = fmaxf(best[q], t);
            }
        }
    }

#pragma unroll
    for (int q = 0; q < PP; ++q) {
        atomicMax(&repmax[pidx[q]], __float_as_uint(best[q]));
    }
}

// ---- Finalize: per-point losses + deterministic block partial sums ----
__device__ inline float wave_reduce(float v) {
#pragma unroll
    for (int off = 32; off > 0; off >>= 1) v += __shfl_down(v, off, 64);
    return v;
}

__global__ __launch_bounds__(256) void finalize_kernel(const float* __restrict__ pred,
                                                       const float* __restrict__ gt,
                                                       const unsigned long long* __restrict__ keys,
                                                       const unsigned int* __restrict__ repmax,
                                                       float* __restrict__ partials) {
    const int p = blockIdx.x * blockDim.x + threadIdx.x;

    const unsigned long long key = keys[p];
    const int j = (int)(key & 0xFFFFFFFFull);

    const float px = pred[p * 6 + 0], py = pred[p * 6 + 1], pz = pred[p * 6 + 2];
    const float gx = gt[j * 6 + 0],  gy = gt[j * 6 + 1],  gz = gt[j * 6 + 2];
    const float dx = px - gx, dy = py - gy, dz = pz - gz;
    float att = dx * dx + dy * dy + dz * dz;   // summed over 3 coords

    const float pnx = pred[p * 6 + 3], pny = pred[p * 6 + 4], pnz = pred[p * 6 + 5];
    const float gnx = gt[j * 6 + 3],   gny = gt[j * 6 + 4],   gnz = gt[j * 6 + 5];
    const float pl = fmaxf(sqrtf(pnx * pnx + pny * pny + pnz * pnz), 1e-5f);
    const float gl = fmaxf(sqrtf(gnx * gnx + gny * gny + gnz * gnz), 1e-5f);
    const float cosv = (pnx * gnx + pny * gny + pnz * gnz) / (pl * gl);
    float nrm = 1.0f - cosv;

    // d^2 = |pi|^2 + 2C - 2*h_max   (exact cdist algebra)
    const float h = __uint_as_float(repmax[p]);
    float d2 = fmaf(-2.0f, h, px * px + py * py + pz * pz + 2.0f * COFF);
    d2 = fmaxf(d2, 0.0f);
    const float dmin = sqrtf(d2);
    const float x = 100.0f * (0.3f - dmin);
    const float sp = fmaxf(x, 0.0f) + log1pf(expf(-fabsf(x)));
    float rep = sp * sp;

    att = wave_reduce(att);
    nrm = wave_reduce(nrm);
    rep = wave_reduce(rep);

    __shared__ float red[3][4];
    const int wave = threadIdx.x >> 6;
    const int lane = threadIdx.x & 63;
    if (lane == 0) {
        red[0][wave] = att;
        red[1][wave] = nrm;
        red[2][wave] = rep;
    }
    __syncthreads();
    if (threadIdx.x == 0) {
        float a = red[0][0] + red[0][1] + red[0][2] + red[0][3];
        float n = red[1][0] + red[1][1] + red[1][2] + red[1][3];
        float r = red[2][0] + red[2][1] + red[2][2] + red[2][3];
        partials[blockIdx.x * 3 + 0] = a;
        partials[blockIdx.x * 3 + 1] = n;
        partials[blockIdx.x * 3 + 2] = r;
    }
}

__global__ void combine_kernel(const float* __restrict__ partials, float* __restrict__ out) {
    if (threadIdx.x == 0 && blockIdx.x == 0) {
        float a = 0.f, n = 0.f, r = 0.f;
        for (int b = 0; b < 32; ++b) {
            a += partials[b * 3 + 0];
            n += partials[b * 3 + 1];
            r += partials[b * 3 + 2];
        }
        const float attraction = a / (float)(N_PRED * 3);
        const float norm_loss  = n / (float)N_PRED;
        const float repulsion  = r / (float)N_PRED;
        out[0] = attraction + repulsion + 10.0f * norm_loss;
    }
}

extern "C" void kernel_launch(void* const* d_in, const int* in_sizes, int n_in,
                              void* d_out, int out_size, void* d_ws, size_t ws_size,
                              hipStream_t stream) {
    const float* pred = (const float*)d_in[0];   // (8192, 6)
    const float* gt   = (const float*)d_in[3];   // (32768, 6)
    float* out = (float*)d_out;

    char* ws = (char*)d_ws;
    unsigned long long* keys = (unsigned long long*)(ws);
    unsigned int* repmax     = (unsigned int*)(ws + 65536);
    float* partials          = (float*)(ws + 98304);

    init_ws_kernel<<<N_PRED / 256, 256, 0, stream>>>(keys, repmax);
    nn_kernel<<<(N_PRED / PRED_CHUNK) * N_GTC, NN_BLK, 0, stream>>>(pred, gt, keys);
    rep_kernel<<<(N_PRED / PRED_CHUNK) * N_SC, NN_BLK, 0, stream>>>(pred, repmax);
    finalize_kernel<<<N_PRED / 256, 256, 0, stream>>>(pred, gt, keys, repmax, partials);
    combine_kernel<<<1, 64, 0, stream>>>(partials, out);
}